// Round 8
// baseline (219.416 us; speedup 1.0000x reference)
//
#include <hip/hip_runtime.h>
#include <math.h>

typedef __attribute__((ext_vector_type(8))) short s16x8;
typedef __attribute__((ext_vector_type(4))) float f32x4;

__device__ __forceinline__ float b2f(unsigned short u) {
    unsigned int x = ((unsigned int)u) << 16;
    float f; __builtin_memcpy(&f, &x, 4); return f;
}
__device__ __forceinline__ unsigned short f2b(float f) {
    unsigned int x; __builtin_memcpy(&x, &f, 4);
    unsigned int r = x + 0x7FFFu + ((x >> 16) & 1u);
    return (unsigned short)(r >> 16);
}

// async global->LDS, 16B per lane, linear LDS dest (guide §5 / m97)
#define GLDS(g, l) __builtin_amdgcn_global_load_lds( \
    (const __attribute__((address_space(1))) unsigned int*)(g), \
    (__attribute__((address_space(3))) unsigned int*)(l), 16, 0, 0)

// ---------- fused prep: x-transpose, W-transpose, weight-norm, zero-init ----------
// flat grid: [0,4096) txp_x | [4096,4288) txp_w | [4288,4800) wnorm | [4800,4864) init
__global__ __launch_bounds__(256) void prep_k(const float* __restrict__ x, unsigned short* __restrict__ xT,
                                              const float* __restrict__ Wq, const float* __restrict__ Wk,
                                              const float* __restrict__ Wv, unsigned short* __restrict__ WT,
                                              const float* __restrict__ v1, const float* __restrict__ g1,
                                              unsigned short* __restrict__ w1K,
                                              const float* __restrict__ v2, const float* __restrict__ g2,
                                              unsigned short* __restrict__ w2K,
                                              unsigned short* __restrict__ attT, unsigned short* __restrict__ h1T,
                                              float* __restrict__ colD) {
    __shared__ float t[32][33];
    __shared__ float red[256];
    int bid = blockIdx.x, tid = threadIdx.x;
    if (bid < 4096) {               // x [b][c][t] -> xT [b][t][c] bf16
        int tt = bid & 31, ct = (bid >> 5) & 7, b = bid >> 8;
        int col = tid & 31, rq = tid >> 5;
        const float* xb = x + (((size_t)b * 256 + ct * 32) << 10) + (tt << 5);
#pragma unroll
        for (int p = 0; p < 4; ++p) { int r = rq + p * 8; t[r][col] = xb[((size_t)r << 10) + col]; }
        __syncthreads();
        unsigned short* o = xT + ((size_t)b << 18) + ((size_t)(tt << 5) << 8) + (ct << 5);
#pragma unroll
        for (int p = 0; p < 4; ++p) { int tr = rq + p * 8; o[((size_t)tr << 8) + col] = f2b(t[col][tr]); }
    } else if (bid < 4288) {        // W [c][k] -> WT [k][c] bf16 (3 mats)
        int id = bid - 4096;
        int kt = id & 7, ct = (id >> 3) & 7, z = id >> 6;
        const float* W = (z == 0) ? Wq : (z == 1) ? Wk : Wv;
        int col = tid & 31, rq = tid >> 5;
        const float* wb = W + ((ct * 32) << 8) + (kt << 5);
#pragma unroll
        for (int p = 0; p < 4; ++p) { int r = rq + p * 8; t[r][col] = wb[(r << 8) + col]; }
        __syncthreads();
        unsigned short* o = WT + (z << 16) + ((kt << 5) << 8) + (ct << 5);
#pragma unroll
        for (int p = 0; p < 4; ++p) { int tr = rq + p * 8; o[(tr << 8) + col] = f2b(t[col][tr]); }
    } else if (bid < 4800) {        // weight-norm -> wK [kk][o][ci] bf16
        int id = bid - 4288;
        int o = id & 255;
        const float* v = (id >= 256) ? v2 : v1;
        const float* g = (id >= 256) ? g2 : g1;
        unsigned short* wK = (id >= 256) ? w2K : w1K;
        float a0 = v[o * 768 + tid * 3 + 0];
        float a1 = v[o * 768 + tid * 3 + 1];
        float a2 = v[o * 768 + tid * 3 + 2];
        red[tid] = a0 * a0 + a1 * a1 + a2 * a2; __syncthreads();
        for (int off = 128; off > 0; off >>= 1) {
            if (tid < off) red[tid] += red[tid + off];
            __syncthreads();
        }
        float sc = g[o] / sqrtf(red[0]);
        wK[0 * 65536 + o * 256 + tid] = f2b(a0 * sc);
        wK[1 * 65536 + o * 256 + tid] = f2b(a1 * sc);
        wK[2 * 65536 + o * 256 + tid] = f2b(a2 * sc);
    } else {                        // zero pads + colD
        int idx = (bid - 4800) * 256 + tid;  // 0..16383
        colD[idx] = 0.f;
        if (idx < 8192) {
            int b = idx >> 9, r = idx & 511;
            attT[(size_t)b * 262656 + r] = 0;
            h1T[(size_t)b * 262656 + r] = 0;
        }
    }
}

// ---------- generic bf16 MFMA GEMM: C = A . B^T  (A [M][K], B [N][K], K-contiguous) ----------
// 128x128 tile, 512 thr = 8 waves (2M x 4N), each wave 64x32 = 4x2 frags of 16x16x32.
// GLDS modes (0,2,4,5): 3-buffer rotation + COUNTED vmcnt(2) (T4) + one raw s_barrier/step.
//   Safety: stage at iter s writes buf((s+2)%3) == buf((s-1)%3); every wave passed the iter-s
//   barrier, i.e. finished compute(s-1) which was the last reader of that buffer.
// MODE 0: merged q/k/v projections (grid 8,10,16; y<8: q/k, y>=8: v; dead blocks return)
// MODE 2: scores  E = exp(qk/16) bf16, masked->0, skip nt>mt; fused colsum -> colD (atomics)
// MODE 3: PV  A=E reg-staged scaled by 1/colD (kills vscale), B=vT GLDS; 2-buffer split-stage;
//         rowsum fused into the scale step (registers); nt==0 lanes write rows[]
// MODE 4: conv1 (+ blockIdx.z==16: wx softmax over rowsums, independent work)
// MODE 5: conv2 + bias relu + x*(1+wx) residual, relu, out fp32 [o][t]
template<int MODE>
__global__ __launch_bounds__(512) void gemm_k(
        const unsigned short* __restrict__ Ab, const unsigned short* __restrict__ Bb,
        unsigned short* __restrict__ o16, unsigned short* __restrict__ o16b,
        unsigned short* __restrict__ o16c, float* __restrict__ o32,
        const float* __restrict__ bias, const float* __restrict__ bias2,
        const float* __restrict__ bias3, const float* __restrict__ xres,
        const float* __restrict__ wxv, float* __restrict__ wxout, int b0) {
    int tid = threadIdx.x;

    if constexpr (MODE == 4) {      // fused wx block (z==16): softmax_t over rowsums
        if (blockIdx.z == 16) {
            __shared__ float wxr[16];
            int b = (blockIdx.y << 1) + blockIdx.x;
            float2 r = ((const float2*)(xres + ((size_t)b << 10)))[tid];
            float mx = fmaxf(r.x, r.y);
#pragma unroll
            for (int off = 32; off > 0; off >>= 1) mx = fmaxf(mx, __shfl_xor(mx, off, 64));
            if ((tid & 63) == 0) wxr[tid >> 6] = mx;
            __syncthreads();
            float M = wxr[0];
#pragma unroll
            for (int i = 1; i < 8; ++i) M = fmaxf(M, wxr[i]);
            float e0 = expf(r.x - M), e1 = expf(r.y - M);
            float ss = e0 + e1;
#pragma unroll
            for (int off = 32; off > 0; off >>= 1) ss += __shfl_xor(ss, off, 64);
            if ((tid & 63) == 0) wxr[8 + (tid >> 6)] = ss;
            __syncthreads();
            float Z = 0.f;
#pragma unroll
            for (int i = 0; i < 8; ++i) Z += wxr[8 + i];
            ((float2*)(wxout + ((size_t)b << 10)))[tid] = make_float2(e0 / Z, e1 / Z);
            return;
        }
    }

    int nt = blockIdx.x, yy = blockIdx.y, bz = blockIdx.z;
    if constexpr (MODE == 2) { if (nt > yy) return; }
    bool isk = false, isv = false;
    int mt = yy;
    if constexpr (MODE == 0) {
        if (yy < 8) { if (nt >= 4) return; isk = (nt >= 2); nt &= 1; }
        else        { isv = true; mt = yy - 8; }
    }
    int b = b0 + bz;
    int m0 = mt << 7, n0 = nt << 7;
    const unsigned short* A;
    const unsigned short* B;
    if constexpr (MODE == 0) {
        if (isv) { A = Ab + 131072 + 131072; /* dummy, replaced below */ }
        A = isv ? (Bb + 131072) : (Ab + ((size_t)b << 18));          // v: A=WvT
        B = isv ? (Ab + ((size_t)b << 18)) : (isk ? Bb + 65536 : Bb);
    } else if constexpr (MODE == 2) { A = Ab + ((size_t)b << 18); B = Bb + ((size_t)b << 18); }
    else if constexpr (MODE == 3)   { A = Ab + ((size_t)bz << 20); B = Bb + ((size_t)b << 18); }
    else                            { A = Ab + (size_t)b * 262656; B = Bb; }

    int wid = tid >> 6, lane = tid & 63;
    int wr = wid >> 2, wc = wid & 3;            // 2 x 4 waves
    int lrow = lane & 15, koct = lane >> 4;
    int srow = tid >> 2, scol = (tid & 3) << 3; // staging: row 0..127, 8-col group

    __shared__ short As[3][4096];
    __shared__ short Bs[3][4096];

    int ksteps = (MODE == 3) ? ((mt + 1) << 2) : 8;
    constexpr int NSEG = (MODE >= 4) ? 3 : 1;
    int total = NSEG * ksteps;

    f32x4 acc[4][2];
#pragma unroll
    for (int m = 0; m < 4; ++m)
#pragma unroll
        for (int n = 0; n < 2; ++n) acc[m][n] = (f32x4){0.f, 0.f, 0.f, 0.f};

    float racc = 0.f;

    if constexpr (MODE == 3) {
        // ---- 2-buffer split-stage: A reg-staged (scaled by 1/colD), B via GLDS ----
        const unsigned short* Arow = A + (size_t)(m0 + srow) * 1024 + scol;
        const unsigned short* Brow = B + (size_t)(n0 + srow) * 1024 + scol;
        const float* drow = bias + (b << 10) + scol;   // colD
        s16x8 areg; float4 dA0, dA1;
        auto ldA = [&](int s) {
            int k0 = s << 5;
            areg = *(const s16x8*)(Arow + k0);
            dA0 = *(const float4*)(drow + k0);
            dA1 = *(const float4*)(drow + k0 + 4);
        };
        auto scaleWrite = [&](int bufi) {
            float dv[8] = {dA0.x, dA0.y, dA0.z, dA0.w, dA1.x, dA1.y, dA1.z, dA1.w};
            s16x8 wv;
#pragma unroll
            for (int c = 0; c < 8; ++c) {
                float p = b2f((unsigned short)areg[c]) / dv[c];
                racc += p;
                wv[c] = (short)f2b(p);
            }
            *(s16x8*)&As[bufi][tid << 3] = wv;
        };
        ldA(0);
        GLDS(Brow, &Bs[0][tid << 3]);
        asm volatile("s_waitcnt vmcnt(0)" ::: "memory");
        scaleWrite(0);
        asm volatile("s_waitcnt lgkmcnt(0)" ::: "memory");
        __builtin_amdgcn_s_barrier();
        int cur = 0;
        for (int s = 0; s < total; ++s) {
            if (s + 1 < total) {
                ldA(s + 1);
                GLDS(Brow + ((s + 1) << 5), &Bs[cur ^ 1][tid << 3]);
            }
            const short* as = &As[cur][0];
            const short* bs = &Bs[cur][0];
            s16x8 af[4], bf[2];
#pragma unroll
            for (int m = 0; m < 4; ++m)
                af[m] = *(const s16x8*)&as[(wr * 64 + m * 16 + lrow) * 32 + (koct << 3)];
#pragma unroll
            for (int n = 0; n < 2; ++n)
                bf[n] = *(const s16x8*)&bs[(wc * 32 + n * 16 + lrow) * 32 + (koct << 3)];
#pragma unroll
            for (int m = 0; m < 4; ++m)
#pragma unroll
                for (int n = 0; n < 2; ++n)
                    acc[m][n] = __builtin_amdgcn_mfma_f32_16x16x32_bf16(af[m], bf[n], acc[m][n], 0, 0, 0);
            if (s + 1 < total) {
                asm volatile("s_waitcnt vmcnt(0)" ::: "memory");
                scaleWrite(cur ^ 1);
                asm volatile("s_waitcnt lgkmcnt(0)" ::: "memory");
                __builtin_amdgcn_s_barrier();
            }
            cur ^= 1;
        }
        // rowsum: racc covers (srow, 8 cols); combine the 4 threads sharing srow
        if (nt == 0) {
            float v = racc;
            v += __shfl_xor(v, 1, 64);
            v += __shfl_xor(v, 2, 64);
            if ((tid & 3) == 0) o32[(b << 10) + m0 + srow] = v;
        }
    } else {
        // ---- 3-buffer GLDS pipeline, counted vmcnt(2) ----
        auto stage_to = [&](int s, int bufi) {
            const unsigned short *ga, *gb;
            if constexpr (MODE >= 4) {
                int seg = s >> 3, k0 = (s & 7) << 5;
                ga = A + (size_t)(m0 + seg + srow) * 256 + k0 + scol;
                gb = B + (seg << 16) + (size_t)(n0 + srow) * 256 + k0 + scol;
            } else {
                int k0 = s << 5;
                ga = A + (size_t)(m0 + srow) * 256 + k0 + scol;
                gb = B + (size_t)(n0 + srow) * 256 + k0 + scol;
            }
            GLDS(ga, &As[bufi][tid << 3]);
            GLDS(gb, &Bs[bufi][tid << 3]);
        };
        stage_to(0, 0);
        stage_to(1, 1);
        for (int s = 0; s < total; ++s) {
            if (s + 1 < total) asm volatile("s_waitcnt vmcnt(2)" ::: "memory");
            else               asm volatile("s_waitcnt vmcnt(0)" ::: "memory");
            __builtin_amdgcn_s_barrier();
            if (s + 2 < total) stage_to(s + 2, (s + 2) % 3);
            const short* as = &As[s % 3][0];
            const short* bs = &Bs[s % 3][0];
            s16x8 af[4], bf[2];
#pragma unroll
            for (int m = 0; m < 4; ++m)
                af[m] = *(const s16x8*)&as[(wr * 64 + m * 16 + lrow) * 32 + (koct << 3)];
#pragma unroll
            for (int n = 0; n < 2; ++n)
                bf[n] = *(const s16x8*)&bs[(wc * 32 + n * 16 + lrow) * 32 + (koct << 3)];
#pragma unroll
            for (int m = 0; m < 4; ++m)
#pragma unroll
                for (int n = 0; n < 2; ++n)
                    acc[m][n] = __builtin_amdgcn_mfma_f32_16x16x32_bf16(af[m], bf[n], acc[m][n], 0, 0, 0);
        }
    }

    int rb = m0 + wr * 64 + koct * 4;
    int cb = n0 + wc * 32 + lrow;

    if constexpr (MODE == 2) {
        float csum[2] = {0.f, 0.f};
#pragma unroll
        for (int m = 0; m < 4; ++m) {
#pragma unroll
            for (int n = 0; n < 2; ++n) {
                int col = cb + n * 16;
#pragma unroll
                for (int j = 0; j < 4; ++j) {
                    int row = rb + m * 16 + j;
                    float e = (col <= row) ? expf(acc[m][n][j] * 0.0625f) : 0.f;
                    o16[((size_t)bz << 20) + ((size_t)row << 10) + col] = f2b(e);
                    csum[n] += e;
                }
            }
        }
#pragma unroll
        for (int n = 0; n < 2; ++n) {
            float v = csum[n];
            v += __shfl_xor(v, 16, 64);
            v += __shfl_xor(v, 32, 64);
            if (koct == 0) atomicAdd(&o32[(b << 10) + cb + n * 16], v);
        }
        return;
    }

#pragma unroll
    for (int m = 0; m < 4; ++m) {
#pragma unroll
        for (int n = 0; n < 2; ++n) {
            int col = cb + n * 16;
#pragma unroll
            for (int j = 0; j < 4; ++j) {
                int row = rb + m * 16 + j;
                float v = acc[m][n][j];
                if constexpr (MODE == 0) {
                    if (isv)       o16c[((size_t)b << 18) + ((size_t)row << 10) + col] = f2b(v + bias3[row]);
                    else if (isk)  o16b[((size_t)b << 18) + ((size_t)row << 8) + col] = f2b(v + bias2[col]);
                    else           o16 [((size_t)b << 18) + ((size_t)row << 8) + col] = f2b(v + bias[col]);
                } else if constexpr (MODE == 3) {
                    o16[(size_t)b * 262656 + ((size_t)(row + 2) << 8) + col] = f2b(v);
                } else if constexpr (MODE == 4) {
                    o16[(size_t)b * 262656 + ((size_t)(row + 2) << 8) + col] =
                        f2b(fmaxf(v + bias[col], 0.f));
                } else if constexpr (MODE == 5) {
                    size_t oi = (((size_t)(b << 8) + col) << 10) + row;
                    float h = fmaxf(v + bias[col], 0.f);
                    h = fmaxf(h + xres[oi] * (1.f + wxv[(b << 10) + row]), 0.f);
                    o32[oi] = h;
                }
            }
        }
    }
}

extern "C" void kernel_launch(void* const* d_in, const int* in_sizes, int n_in,
                              void* d_out, int out_size, void* d_ws, size_t ws_size,
                              hipStream_t stream) {
    const float* x   = (const float*)d_in[0];
    const float* Wq  = (const float*)d_in[1];
    const float* bq  = (const float*)d_in[2];
    const float* Wk  = (const float*)d_in[3];
    const float* bk  = (const float*)d_in[4];
    const float* Wv  = (const float*)d_in[5];
    const float* bv  = (const float*)d_in[6];
    const float* c1v = (const float*)d_in[7];
    const float* c1g = (const float*)d_in[8];
    const float* c1b = (const float*)d_in[9];
    const float* c2v = (const float*)d_in[10];
    const float* c2g = (const float*)d_in[11];
    const float* c2b = (const float*)d_in[12];
    float* out = (float*)d_out;

    // ws layout in BYTES (all regions disjoint)
    char* w = (char*)d_ws;
    unsigned short* xT   = (unsigned short*)(w + 0);          // 8,388,608
    unsigned short* qb   = (unsigned short*)(w + 8388608);    // 8,388,608
    unsigned short* kb   = (unsigned short*)(w + 16777216);   // 8,388,608
    unsigned short* vT   = (unsigned short*)(w + 25165824);   // 8,388,608
    unsigned short* WT   = (unsigned short*)(w + 33554432);   //   393,216
    unsigned short* w1K  = (unsigned short*)(w + 33947648);   //   393,216
    unsigned short* w2K  = (unsigned short*)(w + 34340864);   //   393,216
    unsigned short* attT = (unsigned short*)(w + 34734080);   // 8,404,992 (1026 rows/b)
    unsigned short* h1T  = (unsigned short*)(w + 43139072);   // 8,404,992
    float* colD = (float*)(w + 51544064);                     //    65,536
    float* rows = (float*)(w + 51675136);                     //    65,536
    float* wxp  = (float*)(w + 51740672);                     //    65,536
    unsigned short* S = (unsigned short*)(w + 51806208);      // nb * 2,097,152

    dim3 blk(256), blk2(512);

    prep_k<<<dim3(4864), blk, 0, stream>>>(x, xT, Wq, Wk, Wv, WT,
                                           c1v, c1g, w1K, c2v, c2g, w2K,
                                           attT, h1T, colD);

    // merged q/k/v projections
    gemm_k<0><<<dim3(8, 10, 16), blk2, 0, stream>>>(xT, WT, qb, kb, vT, nullptr,
                                                    bq, bk, bv, nullptr, nullptr, nullptr, 0);

    // chunk the 2 MB/batch E buffer by available ws (deterministic in ws_size)
    size_t fixed = 51806208;
    size_t avail = (ws_size > fixed) ? ws_size - fixed : 0;
    int bmax = (int)(avail / 2097152);
    if (bmax < 1) bmax = 1;
    if (bmax > 16) bmax = 16;
    for (int b0 = 0; b0 < 16; b0 += bmax) {
        int nb = (16 - b0 < bmax) ? (16 - b0) : bmax;
        gemm_k<2><<<dim3(8, 8, nb), blk2, 0, stream>>>(qb, kb, S, nullptr, nullptr, colD,
                                                       nullptr, nullptr, nullptr, nullptr,
                                                       nullptr, nullptr, b0);
        gemm_k<3><<<dim3(2, 8, nb), blk2, 0, stream>>>(S, vT, attT, nullptr, nullptr, rows,
                                                       colD, nullptr, nullptr, nullptr,
                                                       nullptr, nullptr, b0);
    }
    // conv1 (+ wx in z==16 slice)
    gemm_k<4><<<dim3(2, 8, 17), blk2, 0, stream>>>(attT, w1K, h1T, nullptr, nullptr, nullptr,
                                                   c1b, nullptr, nullptr, rows, nullptr, wxp, 0);
    gemm_k<5><<<dim3(2, 8, 16), blk2, 0, stream>>>(h1T, w2K, nullptr, nullptr, nullptr, out,
                                                   c2b, nullptr, nullptr, x, wxp, nullptr, 0);
}

// Round 9
// 206.742 us; speedup vs baseline: 1.0613x; 1.0613x over previous
//
#include <hip/hip_runtime.h>
#include <math.h>

typedef __attribute__((ext_vector_type(8))) short s16x8;
typedef __attribute__((ext_vector_type(4))) float f32x4;

__device__ __forceinline__ float b2f(unsigned short u) {
    unsigned int x = ((unsigned int)u) << 16;
    float f; __builtin_memcpy(&f, &x, 4); return f;
}
__device__ __forceinline__ unsigned short f2b(float f) {
    unsigned int x; __builtin_memcpy(&x, &f, 4);
    unsigned int r = x + 0x7FFFu + ((x >> 16) & 1u);
    return (unsigned short)(r >> 16);
}

// async global->LDS, 16B per lane, linear LDS dest (guide §5 / m97)
#define GLDS(g, l) __builtin_amdgcn_global_load_lds( \
    (const __attribute__((address_space(1))) unsigned int*)(g), \
    (__attribute__((address_space(3))) unsigned int*)(l), 16, 0, 0)

// ---------- fused prep: x-transpose, W-transpose, weight-norm, zero-init ----------
// flat grid: [0,4096) txp_x | [4096,4288) txp_w | [4288,4800) wnorm | [4800,4864) init
__global__ __launch_bounds__(256) void prep_k(const float* __restrict__ x, unsigned short* __restrict__ xT,
                                              const float* __restrict__ Wq, const float* __restrict__ Wk,
                                              const float* __restrict__ Wv, unsigned short* __restrict__ WT,
                                              const float* __restrict__ v1, const float* __restrict__ g1,
                                              unsigned short* __restrict__ w1K,
                                              const float* __restrict__ v2, const float* __restrict__ g2,
                                              unsigned short* __restrict__ w2K,
                                              unsigned short* __restrict__ attT, unsigned short* __restrict__ h1T,
                                              float* __restrict__ colD) {
    __shared__ float t[32][33];
    __shared__ float red[256];
    int bid = blockIdx.x, tid = threadIdx.x;
    if (bid < 4096) {               // x [b][c][t] -> xT [b][t][c] bf16
        int tt = bid & 31, ct = (bid >> 5) & 7, b = bid >> 8;
        int col = tid & 31, rq = tid >> 5;
        const float* xb = x + (((size_t)b * 256 + ct * 32) << 10) + (tt << 5);
#pragma unroll
        for (int p = 0; p < 4; ++p) { int r = rq + p * 8; t[r][col] = xb[((size_t)r << 10) + col]; }
        __syncthreads();
        unsigned short* o = xT + ((size_t)b << 18) + ((size_t)(tt << 5) << 8) + (ct << 5);
#pragma unroll
        for (int p = 0; p < 4; ++p) { int tr = rq + p * 8; o[((size_t)tr << 8) + col] = f2b(t[col][tr]); }
    } else if (bid < 4288) {        // W [c][k] -> WT [k][c] bf16 (3 mats)
        int id = bid - 4096;
        int kt = id & 7, ct = (id >> 3) & 7, z = id >> 6;
        const float* W = (z == 0) ? Wq : (z == 1) ? Wk : Wv;
        int col = tid & 31, rq = tid >> 5;
        const float* wb = W + ((ct * 32) << 8) + (kt << 5);
#pragma unroll
        for (int p = 0; p < 4; ++p) { int r = rq + p * 8; t[r][col] = wb[(r << 8) + col]; }
        __syncthreads();
        unsigned short* o = WT + (z << 16) + ((kt << 5) << 8) + (ct << 5);
#pragma unroll
        for (int p = 0; p < 4; ++p) { int tr = rq + p * 8; o[(tr << 8) + col] = f2b(t[col][tr]); }
    } else if (bid < 4800) {        // weight-norm -> wK [kk][o][ci] bf16
        int id = bid - 4288;
        int o = id & 255;
        const float* v = (id >= 256) ? v2 : v1;
        const float* g = (id >= 256) ? g2 : g1;
        unsigned short* wK = (id >= 256) ? w2K : w1K;
        float a0 = v[o * 768 + tid * 3 + 0];
        float a1 = v[o * 768 + tid * 3 + 1];
        float a2 = v[o * 768 + tid * 3 + 2];
        red[tid] = a0 * a0 + a1 * a1 + a2 * a2; __syncthreads();
        for (int off = 128; off > 0; off >>= 1) {
            if (tid < off) red[tid] += red[tid + off];
            __syncthreads();
        }
        float sc = g[o] / sqrtf(red[0]);
        wK[0 * 65536 + o * 256 + tid] = f2b(a0 * sc);
        wK[1 * 65536 + o * 256 + tid] = f2b(a1 * sc);
        wK[2 * 65536 + o * 256 + tid] = f2b(a2 * sc);
    } else {                        // zero pads + colD
        int idx = (bid - 4800) * 256 + tid;  // 0..16383
        colD[idx] = 0.f;
        if (idx < 8192) {
            int b = idx >> 9, r = idx & 511;
            attT[(size_t)b * 262656 + r] = 0;
            h1T[(size_t)b * 262656 + r] = 0;
        }
    }
}

// ---------- generic bf16 MFMA GEMM: C = A . B^T  (A [M][K], B [N][K], K-contiguous) ----------
// 128x128 tile, 512 thr = 8 waves (2M x 4N), each wave 64x32 = 4x2 frags of 16x16x32.
// 3-buffer GLDS rotation + COUNTED vmcnt(2) (T4) + one raw s_barrier per k-step.
//   Safety: stage(s) writes buf(s%3); buf(s%3) is next overwritten by stage(s+3), issued
//   at iter s+1 AFTER the iter-s+1 barrier; all iter-s reads of buf(s%3) were issued
//   before that barrier.
// LDS bank swizzle (T2, rule #21): physical 16B-slot p of row r holds global slot
//   p ^ ((r>>1)&3). Staging: linear LDS dest + pre-swizzled GLOBAL source column.
//   Read: slot = koct ^ ((lrow>>1)&3) (per-lane constant). Spreads each 16-lane phase
//   across all 8 bank-quads -> 2 lanes/quad (free, m136).
// MODE 0: merged q/k/v projections (grid 8,10,16; y<8: q/k, y>=8: v; dead blocks return)
// MODE 2: scores  E = exp(qk/16) bf16, masked->0, skip nt>mt; fused colsum -> colD (atomics)
// MODE 3: PV  A=E, B=vTs(=v/colD, pre-scaled by vscale_k), K=(mt+1)*128; nt==0 blocks fuse
//         rowsum[j] = sum_i E[j][i] * Rs[i] from the LDS-resident E tile (bias=colD, o32=rows)
// MODE 4: conv1 (+ blockIdx.z==16: wx softmax over rowsums, independent work)
// MODE 5: conv2 + bias relu + x*(1+wx) residual, relu, out fp32 [o][t]
template<int MODE>
__global__ __launch_bounds__(512) void gemm_k(
        const unsigned short* __restrict__ Ab, const unsigned short* __restrict__ Bb,
        unsigned short* __restrict__ o16, unsigned short* __restrict__ o16b,
        unsigned short* __restrict__ o16c, float* __restrict__ o32,
        const float* __restrict__ bias, const float* __restrict__ bias2,
        const float* __restrict__ bias3, const float* __restrict__ xres,
        const float* __restrict__ wxv, float* __restrict__ wxout, int b0) {
    int tid = threadIdx.x;

    if constexpr (MODE == 4) {      // fused wx block (z==16): softmax_t over rowsums
        if (blockIdx.z == 16) {
            __shared__ float wxr[16];
            int b = (blockIdx.y << 1) + blockIdx.x;
            float2 r = ((const float2*)(xres + ((size_t)b << 10)))[tid];
            float mx = fmaxf(r.x, r.y);
#pragma unroll
            for (int off = 32; off > 0; off >>= 1) mx = fmaxf(mx, __shfl_xor(mx, off, 64));
            if ((tid & 63) == 0) wxr[tid >> 6] = mx;
            __syncthreads();
            float M = wxr[0];
#pragma unroll
            for (int i = 1; i < 8; ++i) M = fmaxf(M, wxr[i]);
            float e0 = expf(r.x - M), e1 = expf(r.y - M);
            float ss = e0 + e1;
#pragma unroll
            for (int off = 32; off > 0; off >>= 1) ss += __shfl_xor(ss, off, 64);
            if ((tid & 63) == 0) wxr[8 + (tid >> 6)] = ss;
            __syncthreads();
            float Z = 0.f;
#pragma unroll
            for (int i = 0; i < 8; ++i) Z += wxr[8 + i];
            ((float2*)(wxout + ((size_t)b << 10)))[tid] = make_float2(e0 / Z, e1 / Z);
            return;
        }
    }

    int nt = blockIdx.x, yy = blockIdx.y, bz = blockIdx.z;
    if constexpr (MODE == 2) { if (nt > yy) return; }
    bool isk = false, isv = false;
    int mt = yy;
    if constexpr (MODE == 0) {
        if (yy < 8) { if (nt >= 4) return; isk = (nt >= 2); nt &= 1; }
        else        { isv = true; mt = yy - 8; }
    }
    int b = b0 + bz;
    int m0 = mt << 7, n0 = nt << 7;
    constexpr int LDA = (MODE == 3) ? 1024 : 256;
    constexpr int LDB = (MODE == 3) ? 1024 : 256;
    const unsigned short* A;
    const unsigned short* B;
    if constexpr (MODE == 0) {
        A = isv ? (Bb + 131072) : (Ab + ((size_t)b << 18));          // v: A = WvT
        B = isv ? (Ab + ((size_t)b << 18)) : (isk ? Bb + 65536 : Bb);
    } else if constexpr (MODE == 2) { A = Ab + ((size_t)b << 18); B = Bb + ((size_t)b << 18); }
    else if constexpr (MODE == 3)   { A = Ab + ((size_t)bz << 20); B = Bb + ((size_t)b << 18); }
    else                            { A = Ab + (size_t)b * 262656; B = Bb; }

    int wid = tid >> 6, lane = tid & 63;
    int wr = wid >> 2, wc = wid & 3;            // 2 x 4 waves
    int lrow = lane & 15, koct = lane >> 4;
    int srow = tid >> 2;                        // staging row 0..127
    int sscol = ((tid & 3) ^ ((srow >> 1) & 3)) << 3;  // pre-swizzled global col (shorts)
    int rswz = (koct ^ ((lrow >> 1) & 3)) << 3;        // swizzled read slot (per-lane const)

    __shared__ short As[3][4096];
    __shared__ short Bs[3][4096];
    __shared__ float Rs[(MODE == 3) ? 1024 : 1];

    int ksteps = (MODE == 3) ? ((mt + 1) << 2) : 8;
    constexpr int NSEG = (MODE >= 4) ? 3 : 1;
    int total = NSEG * ksteps;

    if constexpr (MODE == 3) {
        if (nt == 0) {
            for (int i = tid; i < (ksteps << 5); i += 512)
                Rs[i] = 1.f / bias[(b << 10) + i];
            __syncthreads();
        }
    }
    float racc = 0.f;

    f32x4 acc[4][2];
#pragma unroll
    for (int m = 0; m < 4; ++m)
#pragma unroll
        for (int n = 0; n < 2; ++n) acc[m][n] = (f32x4){0.f, 0.f, 0.f, 0.f};

    auto stage_to = [&](int s, int bufi) {
        const unsigned short *ga, *gb;
        if constexpr (MODE >= 4) {
            int seg = s >> 3, k0 = (s & 7) << 5;
            ga = A + (size_t)(m0 + seg + srow) * 256 + k0 + sscol;
            gb = B + (seg << 16) + (size_t)(n0 + srow) * 256 + k0 + sscol;
        } else {
            int k0 = s << 5;
            ga = A + (size_t)(m0 + srow) * LDA + k0 + sscol;
            gb = B + (size_t)(n0 + srow) * LDB + k0 + sscol;
        }
        GLDS(ga, &As[bufi][tid << 3]);
        GLDS(gb, &Bs[bufi][tid << 3]);
    };

    stage_to(0, 0);
    stage_to(1, 1);
    for (int s = 0; s < total; ++s) {
        if (s + 1 < total) asm volatile("s_waitcnt vmcnt(2)" ::: "memory");
        else               asm volatile("s_waitcnt vmcnt(0)" ::: "memory");
        __builtin_amdgcn_s_barrier();
        if (s + 2 < total) stage_to(s + 2, (s + 2) % 3);
        const short* as = &As[s % 3][0];
        const short* bs = &Bs[s % 3][0];
        s16x8 af[4], bf[2];
#pragma unroll
        for (int m = 0; m < 4; ++m)
            af[m] = *(const s16x8*)&as[(wr * 64 + m * 16 + lrow) * 32 + rswz];
#pragma unroll
        for (int n = 0; n < 2; ++n)
            bf[n] = *(const s16x8*)&bs[(wc * 32 + n * 16 + lrow) * 32 + rswz];
#pragma unroll
        for (int m = 0; m < 4; ++m)
#pragma unroll
            for (int n = 0; n < 2; ++n)
                acc[m][n] = __builtin_amdgcn_mfma_f32_16x16x32_bf16(af[m], bf[n], acc[m][n], 0, 0, 0);
        if constexpr (MODE == 3) {
            if (nt == 0) {   // fused rowsum from the LDS-resident E tile (swizzled read)
                int k0 = s << 5;
                int rrow = tid >> 2, slot = tid & 3;
                const s16x8 e0 = *(const s16x8*)&as[rrow * 32 + ((slot ^ ((rrow >> 1) & 3)) << 3)];
#pragma unroll
                for (int c = 0; c < 8; ++c)
                    racc += b2f((unsigned short)e0[c]) * Rs[k0 + (slot << 3) + c];
            }
        }
    }

    if constexpr (MODE == 3) {
        if (nt == 0) {
            float v = racc;
            v += __shfl_xor(v, 1, 64);
            v += __shfl_xor(v, 2, 64);
            if ((tid & 3) == 0) o32[(b << 10) + m0 + (tid >> 2)] = v;
        }
    }

    int rb = m0 + wr * 64 + koct * 4;
    int cb = n0 + wc * 32 + lrow;

    if constexpr (MODE == 2) {
        float csum[2] = {0.f, 0.f};
#pragma unroll
        for (int m = 0; m < 4; ++m) {
#pragma unroll
            for (int n = 0; n < 2; ++n) {
                int col = cb + n * 16;
#pragma unroll
                for (int j = 0; j < 4; ++j) {
                    int row = rb + m * 16 + j;
                    float e = (col <= row) ? expf(acc[m][n][j] * 0.0625f) : 0.f;
                    o16[((size_t)bz << 20) + ((size_t)row << 10) + col] = f2b(e);
                    csum[n] += e;
                }
            }
        }
#pragma unroll
        for (int n = 0; n < 2; ++n) {
            float v = csum[n];
            v += __shfl_xor(v, 16, 64);
            v += __shfl_xor(v, 32, 64);
            if (koct == 0) atomicAdd(&o32[(b << 10) + cb + n * 16], v);
        }
        return;
    }

#pragma unroll
    for (int m = 0; m < 4; ++m) {
#pragma unroll
        for (int n = 0; n < 2; ++n) {
            int col = cb + n * 16;
#pragma unroll
            for (int j = 0; j < 4; ++j) {
                int row = rb + m * 16 + j;
                float v = acc[m][n][j];
                if constexpr (MODE == 0) {
                    if (isv)       o16c[((size_t)b << 18) + ((size_t)row << 10) + col] = f2b(v + bias3[row]);
                    else if (isk)  o16b[((size_t)b << 18) + ((size_t)row << 8) + col] = f2b(v + bias2[col]);
                    else           o16 [((size_t)b << 18) + ((size_t)row << 8) + col] = f2b(v + bias[col]);
                } else if constexpr (MODE == 3) {
                    o16[(size_t)b * 262656 + ((size_t)(row + 2) << 8) + col] = f2b(v);
                } else if constexpr (MODE == 4) {
                    o16[(size_t)b * 262656 + ((size_t)(row + 2) << 8) + col] =
                        f2b(fmaxf(v + bias[col], 0.f));
                } else if constexpr (MODE == 5) {
                    size_t oi = (((size_t)(b << 8) + col) << 10) + row;
                    float h = fmaxf(v + bias[col], 0.f);
                    h = fmaxf(h + xres[oi] * (1.f + wxv[(b << 10) + row]), 0.f);
                    o32[oi] = h;
                }
            }
        }
    }
}

// ---------- vTs = vT / colD (in place, per key index i) ----------
__global__ __launch_bounds__(256) void vscale_k(unsigned short* __restrict__ vT,
                                                const float* __restrict__ colD, int b0) {
    int c = blockIdx.x, bz = blockIdx.y, b = b0 + bz;
    int tid = threadIdx.x;
    unsigned short* row = vT + ((size_t)b << 18) + ((size_t)c << 10);
    ushort4 v4 = *(const ushort4*)&row[tid << 2];
    float4 d4 = ((const float4*)(colD + (b << 10)))[tid];
    ushort4 o;
    o.x = f2b(b2f(v4.x) / d4.x);
    o.y = f2b(b2f(v4.y) / d4.y);
    o.z = f2b(b2f(v4.z) / d4.z);
    o.w = f2b(b2f(v4.w) / d4.w);
    *(ushort4*)&row[tid << 2] = o;
}

extern "C" void kernel_launch(void* const* d_in, const int* in_sizes, int n_in,
                              void* d_out, int out_size, void* d_ws, size_t ws_size,
                              hipStream_t stream) {
    const float* x   = (const float*)d_in[0];
    const float* Wq  = (const float*)d_in[1];
    const float* bq  = (const float*)d_in[2];
    const float* Wk  = (const float*)d_in[3];
    const float* bk  = (const float*)d_in[4];
    const float* Wv  = (const float*)d_in[5];
    const float* bv  = (const float*)d_in[6];
    const float* c1v = (const float*)d_in[7];
    const float* c1g = (const float*)d_in[8];
    const float* c1b = (const float*)d_in[9];
    const float* c2v = (const float*)d_in[10];
    const float* c2g = (const float*)d_in[11];
    const float* c2b = (const float*)d_in[12];
    float* out = (float*)d_out;

    // ws layout in BYTES (all regions disjoint)
    char* w = (char*)d_ws;
    unsigned short* xT   = (unsigned short*)(w + 0);          // 8,388,608
    unsigned short* qb   = (unsigned short*)(w + 8388608);    // 8,388,608
    unsigned short* kb   = (unsigned short*)(w + 16777216);   // 8,388,608
    unsigned short* vT   = (unsigned short*)(w + 25165824);   // 8,388,608
    unsigned short* WT   = (unsigned short*)(w + 33554432);   //   393,216
    unsigned short* w1K  = (unsigned short*)(w + 33947648);   //   393,216
    unsigned short* w2K  = (unsigned short*)(w + 34340864);   //   393,216
    unsigned short* attT = (unsigned short*)(w + 34734080);   // 8,404,992 (1026 rows/b)
    unsigned short* h1T  = (unsigned short*)(w + 43139072);   // 8,404,992
    float* colD = (float*)(w + 51544064);                     //    65,536
    float* rows = (float*)(w + 51675136);                     //    65,536
    float* wxp  = (float*)(w + 51740672);                     //    65,536
    unsigned short* S = (unsigned short*)(w + 51806208);      // nb * 2,097,152

    dim3 blk(256), blk2(512);

    prep_k<<<dim3(4864), blk, 0, stream>>>(x, xT, Wq, Wk, Wv, WT,
                                           c1v, c1g, w1K, c2v, c2g, w2K,
                                           attT, h1T, colD);

    // merged q/k/v projections
    gemm_k<0><<<dim3(8, 10, 16), blk2, 0, stream>>>(xT, WT, qb, kb, vT, nullptr,
                                                    bq, bk, bv, nullptr, nullptr, nullptr, 0);

    // chunk the 2 MB/batch E buffer by available ws (deterministic in ws_size)
    size_t fixed = 51806208;
    size_t avail = (ws_size > fixed) ? ws_size - fixed : 0;
    int bmax = (int)(avail / 2097152);
    if (bmax < 1) bmax = 1;
    if (bmax > 16) bmax = 16;
    for (int b0 = 0; b0 < 16; b0 += bmax) {
        int nb = (16 - b0 < bmax) ? (16 - b0) : bmax;
        gemm_k<2><<<dim3(8, 8, nb), blk2, 0, stream>>>(qb, kb, S, nullptr, nullptr, colD,
                                                       nullptr, nullptr, nullptr, nullptr,
                                                       nullptr, nullptr, b0);
        vscale_k<<<dim3(256, nb), blk, 0, stream>>>(vT, colD, b0);
        gemm_k<3><<<dim3(2, 8, nb), blk2, 0, stream>>>(S, vT, attT, nullptr, nullptr, rows,
                                                       colD, nullptr, nullptr, nullptr,
                                                       nullptr, nullptr, b0);
    }
    // conv1 (+ wx in z==16 slice)
    gemm_k<4><<<dim3(2, 8, 17), blk2, 0, stream>>>(attT, w1K, h1T, nullptr, nullptr, nullptr,
                                                   c1b, nullptr, nullptr, rows, nullptr, wxp, 0);
    gemm_k<5><<<dim3(2, 8, 16), blk2, 0, stream>>>(h1T, w2K, nullptr, nullptr, nullptr, out,
                                                   c2b, nullptr, nullptr, x, wxp, nullptr, 0);
}